// Round 4
// baseline (531.259 us; speedup 1.0000x reference)
//
#include <hip/hip_runtime.h>
#include <hip/hip_bf16.h>
#include <math.h>

#define MDIM  128
#define FEAT  8256      // 128*129/2 (elements == bytes in fp8)
#define HID   1651
#define HIDP  1664      // 13*128, zero-padded
#define BATCH 4096
#define BK    64
#define KT_TOTAL 129    // FEAT / BK (full K, no split: relu needs full sum)
#define W1SCALE 8192.0f
#define W1INV   (1.0f / 8192.0f)
#define DEPTH 3         // LDS ring buffers (2-iteration prefetch lead)
#define NBN   13        // bn tiles per bm row-panel

using f32x4  = __attribute__((ext_vector_type(4))) float;
using f32x16 = __attribute__((ext_vector_type(16))) float;
using i32x4  = __attribute__((ext_vector_type(4))) int;
using i32x8  = __attribute__((ext_vector_type(8))) int;
typedef long long i64;

__device__ __forceinline__ void gload_lds16(const void* g, void* l) {
    __builtin_amdgcn_global_load_lds(
        (const __attribute__((address_space(1))) void*)g,
        (__attribute__((address_space(3))) void*)l,
        16, 0, 0);
}

__device__ __forceinline__ int row_off(int i) { return (i * (257 - i)) >> 1; }

// pack 8 floats -> 8 fp8 e4m3 bytes (two ints)
__device__ __forceinline__ void pack8_fp8(const float* f, int* o) {
    int lo = __builtin_amdgcn_cvt_pk_fp8_f32(f[0], f[1], 0, false);
    lo     = __builtin_amdgcn_cvt_pk_fp8_f32(f[2], f[3], lo, true);
    int hi = __builtin_amdgcn_cvt_pk_fp8_f32(f[4], f[5], 0, false);
    hi     = __builtin_amdgcn_cvt_pk_fp8_f32(f[6], f[7], hi, true);
    o[0] = lo; o[1] = hi;
}

// ---------------------------------------------------------------------------
// Kernel 1 (fused prep): blocks [0, BATCH) gather triu(sim) -> X fp8;
// blocks [BATCH, BATCH+5*HIDP) convert W1*8192 -> fp8 [HIDP, FEAT] (rows >=
// HID zeroed); final block zeroes out_pre[4096] + cnt[32] for the GEMM.
// Round-4: vectorized fast path for non-row-crossing groups (j <= 120,
// ~88% of groups) -> 2 wide loads instead of 8 scalar dwords.
// ---------------------------------------------------------------------------
__global__ void __launch_bounds__(256)
prep_kernel(const float* __restrict__ sim, const float* __restrict__ W1,
            char* __restrict__ X, char* __restrict__ W1p,
            float* __restrict__ out_pre, int* __restrict__ cnt) {
    const int t = threadIdx.x;
    if (blockIdx.x < BATCH) {
        const int b = blockIdx.x;
        const float* srow = sim + ((i64)b << 14);
        char* dst = X + (i64)b * FEAT;
#pragma unroll
        for (int it = 0; it < 5; ++it) {
            const int w = it * 256 + t;
            if (w < FEAT / 8) {
                const int f0 = w * 8;
                int i = (int)((257.0f - sqrtf(66049.0f - 8.0f * (float)f0)) * 0.5f);
                i = i < 0 ? 0 : (i > 127 ? 127 : i);
                while (i < 127 && row_off(i + 1) <= f0) ++i;
                while (i > 0 && row_off(i) > f0) --i;
                int j = i + (f0 - row_off(i));
                float v[8];
                if (j <= 120) {
                    // no row crossing: 32 contiguous bytes (dword-aligned)
                    __builtin_memcpy(v, srow + i * MDIM + j, 32);
                } else {
#pragma unroll
                    for (int e = 0; e < 8; ++e) {
                        if (j > 127) { ++i; j = i; }
                        v[e] = srow[i * MDIM + j];
                        ++j;
                    }
                }
                int o[2];
                pack8_fp8(v, o);
                *(int2*)(dst + f0) = make_int2(o[0], o[1]);
            }
        }
    } else if (blockIdx.x < BATCH + 5 * HIDP) {
        const int c  = blockIdx.x - BATCH;   // 0 .. 5*HIDP-1
        const int wb = c % 5;
        const int n  = c / 5;
        const int w  = wb * 256 + t;
        if (w >= FEAT / 8) return;
        const int f0 = w * 8;
        int o[2];
        if (n < HID) {
            const float* src = W1 + (i64)n * FEAT + f0;
            const f32x4 a = *(const f32x4*)src;
            const f32x4 d = *(const f32x4*)(src + 4);
            float v[8];
#pragma unroll
            for (int e = 0; e < 4; ++e) {
                v[e]     = a[e] * W1SCALE;
                v[e + 4] = d[e] * W1SCALE;
            }
            pack8_fp8(v, o);
        } else {
            o[0] = 0; o[1] = 0;
        }
        *(int2*)(W1p + (i64)n * FEAT + f0) = make_int2(o[0], o[1]);
    } else {
        // zero out_pre (4096 floats = 1024 f32x4; 4 per thread) + counters
        const f32x4 zz = {0.f, 0.f, 0.f, 0.f};
        f32x4* p = (f32x4*)out_pre + t * 4;
        p[0] = zz; p[1] = zz; p[2] = zz; p[3] = zz;
        if (t < 32) cnt[t] = 0;
    }
}

// ---------------------------------------------------------------------------
// Kernel 2: full-K MX-scaled fp8 GEMM, 128x128 tile, BK=64, FUSED epilogue
// AND fused sigmoid finisher. Ring pipeline (DEPTH=3) + raw s_barrier +
// counted vmcnt (verified r2/r3). After the K-loop each wave applies
// relu(acc*W1INV + b1)*W2 in-register, half-wave shfl_xor-reduces, and
// atomicAdds one fp32 partial per output row -> out_pre[4096].
// Round-4: the LAST of the NBN=13 blocks per bm (agent-scope completion
// counter, threadfence release / acquire) computes the final sigmoid for its
// 128 rows -> drops the third dispatch. Cross-XCD visibility: counter via
// __hip_atomic_fetch_add(AGENT), row values re-read via agent-scope atomic
// loads (per-XCD L2s are not coherent; plain loads could be stale).
//
// LDS layout (HW-verified r1-r3): phys(row,chunk)=chunk*2048+row*16; staging
// realizes it via per-lane global source chunk choice; fragment reads are
// conflict-free ds_read_b128 pairs.
// ---------------------------------------------------------------------------
__global__ void __launch_bounds__(256, 3)
gemm_fused_kernel(const char* __restrict__ X,
                  const char* __restrict__ W1p,
                  const float* __restrict__ b1,
                  const float* __restrict__ W2,
                  const float* __restrict__ b2,
                  float* __restrict__ out_pre,
                  int* __restrict__ cnt,
                  float* __restrict__ out) {
    __shared__ __align__(16) char lds_a[DEPTH * 8192];   // 24 KB
    __shared__ __align__(16) char lds_b[DEPTH * 8192];   // 24 KB

    const int t    = threadIdx.x;
    const int w    = t >> 6;
    const int l    = t & 63;
    const int bm   = blockIdx.x;
    const int bn   = blockIdx.y;
    const int wm   = w >> 1;          // wave row (0..1) -> 64 output rows
    const int wn   = w & 1;           // wave col (0..1) -> 64 output cols
    const int lm   = l & 31;
    const int c0   = (l >> 5) << 1;   // chunk base for this lane's K-half

    f32x16 acc[2][2];
#pragma unroll
    for (int r = 0; r < 16; ++r) {
        acc[0][0][r] = 0.f; acc[0][1][r] = 0.f;
        acc[1][0][r] = 0.f; acc[1][1][r] = 0.f;
    }

    const int nkt = KT_TOTAL;

    // staging roles: thread t covers row (w&1)*64+l, chunks {(w>>1), (w>>1)+2}
    const int stR = ((w & 1) << 6) + l;
    const char* gA0 = X + (i64)(bm * 128 + stR) * FEAT + (w >> 1) * 16;
    const char* gB0 = W1p + (i64)(bn * 128 + stR) * FEAT + (w >> 1) * 16;
    char* lA = lds_a + w * 1024;      // wave-uniform LDS dest base
    char* lB = lds_b + w * 1024;

    // 4 vmcnt events (global_load_lds) per STAGE per thread
#define STAGE(buf, kidx) do {                                      \
        const char* _ga = gA0 + (i64)(kidx) * BK;                  \
        const char* _gb = gB0 + (i64)(kidx) * BK;                  \
        char* _la = lA + (buf) * 8192;                             \
        char* _lb = lB + (buf) * 8192;                             \
        gload_lds16(_ga,      _la);                                \
        gload_lds16(_ga + 32, _la + 4096);                         \
        gload_lds16(_gb,      _lb);                                \
        gload_lds16(_gb + 32, _lb + 4096);                         \
    } while (0)

    STAGE(0, 0);
    STAGE(1, 1);
    STAGE(2, 2);

    int cur = 0;
    for (int kt = 0; kt < nkt; ++kt) {
        // ready-wait for buf[cur]: drain my oldest stage, keep the rest flying
        if (kt + 3 <= nkt)      asm volatile("s_waitcnt vmcnt(8)" ::: "memory");
        else if (kt + 2 == nkt) asm volatile("s_waitcnt vmcnt(4)" ::: "memory");
        else                    asm volatile("s_waitcnt vmcnt(0)" ::: "memory");
        __builtin_amdgcn_s_barrier();          // all waves' quarters landed
        __builtin_amdgcn_sched_barrier(0);

        const char* pa = lds_a + cur * 8192 + c0 * 2048 + (wm * 64 + lm) * 16;
        const char* pb = lds_b + cur * 8192 + c0 * 2048 + (wn * 64 + lm) * 16;
        i32x8 A0, A1, B0, B1;
        *((i32x4*)&A0)     = *(const i32x4*)(pa);
        *((i32x4*)&A0 + 1) = *(const i32x4*)(pa + 2048);
        *((i32x4*)&A1)     = *(const i32x4*)(pa + 512);
        *((i32x4*)&A1 + 1) = *(const i32x4*)(pa + 512 + 2048);
        *((i32x4*)&B0)     = *(const i32x4*)(pb);
        *((i32x4*)&B0 + 1) = *(const i32x4*)(pb + 2048);
        *((i32x4*)&B1)     = *(const i32x4*)(pb + 512);
        *((i32x4*)&B1 + 1) = *(const i32x4*)(pb + 512 + 2048);

        __builtin_amdgcn_s_setprio(1);
        // fmt 0 = OCP fp8 e4m3; unit scales (0x7F = 2^0) in every byte
        acc[0][0] = __builtin_amdgcn_mfma_scale_f32_32x32x64_f8f6f4(
            A0, B0, acc[0][0], 0, 0, 0, 0x7F7F7F7F, 0, 0x7F7F7F7F);
        acc[0][1] = __builtin_amdgcn_mfma_scale_f32_32x32x64_f8f6f4(
            A0, B1, acc[0][1], 0, 0, 0, 0x7F7F7F7F, 0, 0x7F7F7F7F);
        acc[1][0] = __builtin_amdgcn_mfma_scale_f32_32x32x64_f8f6f4(
            A1, B0, acc[1][0], 0, 0, 0, 0x7F7F7F7F, 0, 0x7F7F7F7F);
        acc[1][1] = __builtin_amdgcn_mfma_scale_f32_32x32x64_f8f6f4(
            A1, B1, acc[1][1], 0, 0, 0, 0x7F7F7F7F, 0, 0x7F7F7F7F);
        __builtin_amdgcn_s_setprio(0);

        // my ds_reads retired before anyone overwrites buf[cur]
        asm volatile("s_waitcnt lgkmcnt(0)" ::: "memory");
        __builtin_amdgcn_sched_barrier(0);
        __builtin_amdgcn_s_barrier();          // all waves done reading cur
        __builtin_amdgcn_sched_barrier(0);

        if (kt + 3 < nkt) STAGE(cur, kt + 3);  // refill oldest slot
        cur = (cur == DEPTH - 1) ? 0 : cur + 1;
    }
#undef STAGE

    // ---- fused epilogue ----
    // C/D mapping: col = lane&31, row = (reg&3) + 8*(reg>>2) + 4*(lane>>5).
    const int colbase = bn * 128 + wn * 64 + lm;
    float b1v[2], w2v[2];
#pragma unroll
    for (int cb = 0; cb < 2; ++cb) {
        const int col = colbase + cb * 32;
        const bool ok = col < HID;          // padded cols contribute 0
        b1v[cb] = ok ? b1[col] : 0.f;
        w2v[cb] = ok ? W2[col] : 0.f;
    }
    const int rbase = bm * 128 + wm * 64 + ((l >> 5) << 2);
#pragma unroll
    for (int rb = 0; rb < 2; ++rb)
#pragma unroll
        for (int reg = 0; reg < 16; ++reg) {
            float v = 0.f;
#pragma unroll
            for (int cb = 0; cb < 2; ++cb) {
                const float pre = acc[rb][cb][reg] * W1INV + b1v[cb];
                v += fmaxf(pre, 0.f) * w2v[cb];
            }
            // reduce over this half-wave's 32 columns (masks stay in-half)
            v += __shfl_xor(v, 1);
            v += __shfl_xor(v, 2);
            v += __shfl_xor(v, 4);
            v += __shfl_xor(v, 8);
            v += __shfl_xor(v, 16);
            if (lm == 0) {
                const int row = rbase + rb * 32 + (reg & 3) + ((reg >> 2) << 3);
                atomicAdd(out_pre + row, v);   // device-scope (m20)
            }
        }

    // ---- fused sigmoid finisher (last of NBN blocks for this bm) ----
    __threadfence();                 // release my out_pre atomics
    __syncthreads();                 // all threads in block fenced
    __shared__ int sdone;
    if (t == 0) {
        const int old = __hip_atomic_fetch_add(
            cnt + bm, 1, __ATOMIC_ACQ_REL, __HIP_MEMORY_SCOPE_AGENT);
        sdone = (old == NBN - 1);
    }
    __syncthreads();
    if (sdone && t < 128) {
        const int row = bm * 128 + t;
        const float v = __hip_atomic_load(
            out_pre + row, __ATOMIC_RELAXED, __HIP_MEMORY_SCOPE_AGENT);
        out[row] = 1.0f / (1.0f + expf(-(v + b2[0])));
    }
}

extern "C" void kernel_launch(void* const* d_in, const int* in_sizes, int n_in,
                              void* d_out, int out_size, void* d_ws, size_t ws_size,
                              hipStream_t stream) {
    const float* sim = (const float*)d_in[0];
    const float* W1  = (const float*)d_in[1];
    const float* b1  = (const float*)d_in[2];
    const float* W2  = (const float*)d_in[3];
    const float* b2  = (const float*)d_in[4];
    float* out = (float*)d_out;

    char* ws = (char*)d_ws;
    const i64 X_OFF   = 0;                           // 33,816,576 B
    const i64 W1P_OFF = (i64)BATCH * FEAT;           // fp8: elems == bytes
    const i64 PRE_OFF = W1P_OFF + (i64)HIDP * FEAT;  // +13,737,984
    const i64 CNT_OFF = PRE_OFF + (i64)BATCH * 4;    // +16,384
    // total: ~47.6 MB << ws bound
    char*  Xf8  = ws + X_OFF;
    char*  W1f8 = ws + W1P_OFF;
    float* pre  = (float*)(ws + PRE_OFF);
    int*   cnt  = (int*)(ws + CNT_OFF);

    prep_kernel<<<BATCH + 5 * HIDP + 1, 256, 0, stream>>>(sim, W1, Xf8, W1f8,
                                                          pre, cnt);
    {
        dim3 grid(BATCH / 128, HIDP / 128);          // (32, 13)
        gemm_fused_kernel<<<grid, 256, 0, stream>>>(Xf8, W1f8, b1, W2, b2,
                                                    pre, cnt, out);
    }
}

// Round 5
// 482.843 us; speedup vs baseline: 1.1003x; 1.1003x over previous
//
#include <hip/hip_runtime.h>
#include <hip/hip_bf16.h>
#include <math.h>

#define MDIM  128
#define FEAT  8256      // 128*129/2 (elements == bytes in fp8)
#define HID   1651
#define HIDP  1664      // 13*128, zero-padded
#define BATCH 4096
#define BK    64
#define KT_TOTAL 129    // FEAT / BK (full K, no split: relu needs full sum)
#define NCHUNK 516      // FEAT/16: 16-byte K-slices
#define W1SCALE 8192.0f
#define W1INV   (1.0f / 8192.0f)
#define DEPTH 3         // LDS ring buffers (2-iteration prefetch lead)

// chunk-major strides (bytes)
#define XT_CSTRIDE  ((i64)BATCH * 16)   // 65536
#define W1T_CSTRIDE ((i64)HIDP * 16)    // 26624

using f32x4  = __attribute__((ext_vector_type(4))) float;
using f32x16 = __attribute__((ext_vector_type(16))) float;
using i32x4  = __attribute__((ext_vector_type(4))) int;
using i32x8  = __attribute__((ext_vector_type(8))) int;
typedef long long i64;

__device__ __forceinline__ void gload_lds16(const void* g, void* l) {
    __builtin_amdgcn_global_load_lds(
        (const __attribute__((address_space(1))) void*)g,
        (__attribute__((address_space(3))) void*)l,
        16, 0, 0);
}

__device__ __forceinline__ int row_off(int i) { return (i * (257 - i)) >> 1; }

// pack 8 floats -> 8 fp8 e4m3 bytes (two ints)
__device__ __forceinline__ void pack8_fp8(const float* f, int* o) {
    int lo = __builtin_amdgcn_cvt_pk_fp8_f32(f[0], f[1], 0, false);
    lo     = __builtin_amdgcn_cvt_pk_fp8_f32(f[2], f[3], lo, true);
    int hi = __builtin_amdgcn_cvt_pk_fp8_f32(f[4], f[5], 0, false);
    hi     = __builtin_amdgcn_cvt_pk_fp8_f32(f[6], f[7], hi, true);
    o[0] = lo; o[1] = hi;
}

// ---------------------------------------------------------------------------
// Kernel 1 (fused prep): blocks [0, BATCH) gather triu(sim) -> X_t fp8
// CHUNK-MAJOR: X_t[chunk][b] (chunk = 16-byte K-slice). Blocks
// [BATCH, BATCH+5*HIDP) convert W1*8192 -> fp8 W1t[chunk][n] (rows >= HID
// zero). Final block zeroes out_pre.
// Chunk-major layouts make the GEMM's global_load_lds staging COALESCED
// (round-4 counters: old row-major staging was 64 lines/instr, TA-bound,
// GEMM 166us @ MfmaUtil 13.6%). Scalar gather restored (r4 memcpy fast
// path regressed ~20us).
// ---------------------------------------------------------------------------
__global__ void __launch_bounds__(256)
prep_kernel(const float* __restrict__ sim, const float* __restrict__ W1,
            char* __restrict__ Xt, char* __restrict__ W1t,
            float* __restrict__ out_pre) {
    const int t = threadIdx.x;
    if (blockIdx.x < BATCH) {
        const int b = blockIdx.x;
        const float* srow = sim + ((i64)b << 14);
#pragma unroll
        for (int it = 0; it < 5; ++it) {
            const int g = it * 256 + t;          // 8-elem group id
            if (g < FEAT / 8) {
                const int f0 = g * 8;
                int i = (int)((257.0f - sqrtf(66049.0f - 8.0f * (float)f0)) * 0.5f);
                i = i < 0 ? 0 : (i > 127 ? 127 : i);
                while (i < 127 && row_off(i + 1) <= f0) ++i;
                while (i > 0 && row_off(i) > f0) --i;
                int j = i + (f0 - row_off(i));
                float v[8];
#pragma unroll
                for (int e = 0; e < 8; ++e) {
                    if (j > 127) { ++i; j = i; }
                    v[e] = srow[i * MDIM + j];
                    ++j;
                }
                int o[2];
                pack8_fp8(v, o);
                // chunk-major store: chunk = g>>1, half = g&1
                *(int2*)(Xt + (i64)(g >> 1) * XT_CSTRIDE + (i64)b * 16
                            + (g & 1) * 8) = make_int2(o[0], o[1]);
            }
        }
    } else if (blockIdx.x < BATCH + 5 * HIDP) {
        const int c  = blockIdx.x - BATCH;   // 0 .. 5*HIDP-1
        const int wb = c % 5;
        const int n  = c / 5;
        const int g  = wb * 256 + t;
        if (g >= FEAT / 8) return;
        const int f0 = g * 8;
        int o[2];
        if (n < HID) {
            const float* src = W1 + (i64)n * FEAT + f0;
            const f32x4 a = *(const f32x4*)src;
            const f32x4 d = *(const f32x4*)(src + 4);
            float v[8];
#pragma unroll
            for (int e = 0; e < 4; ++e) {
                v[e]     = a[e] * W1SCALE;
                v[e + 4] = d[e] * W1SCALE;
            }
            pack8_fp8(v, o);
        } else {
            o[0] = 0; o[1] = 0;
        }
        *(int2*)(W1t + (i64)(g >> 1) * W1T_CSTRIDE + (i64)n * 16
                    + (g & 1) * 8) = make_int2(o[0], o[1]);
    } else {
        // zero out_pre (4096 floats = 1024 f32x4; 4 per thread)
        const f32x4 zz = {0.f, 0.f, 0.f, 0.f};
        f32x4* p = (f32x4*)out_pre + t * 4;
        p[0] = zz; p[1] = zz; p[2] = zz; p[3] = zz;
    }
}

// ---------------------------------------------------------------------------
// Kernel 2: full-K MX-scaled fp8 GEMM, 128x128 tile, BK=64, fused epilogue.
// Ring pipeline (DEPTH=3) + raw s_barrier + counted vmcnt (verified r2/r3).
// Round-5 change: staging sources read CHUNK-MAJOR X_t/W1t -> each
// global_load_lds is 64 lanes x 16B CONTIGUOUS (16 cache lines/instr vs 64
// before). LDS layout phys(row,chunk)=chunk*2048+row*16 and everything
// downstream (ds_read fragments, MFMA, epilogue) is byte-identical to the
// verified r3 kernel.
// ---------------------------------------------------------------------------
__global__ void __launch_bounds__(256, 3)
gemm_fused_kernel(const char* __restrict__ Xt,
                  const char* __restrict__ W1t,
                  const float* __restrict__ b1,
                  const float* __restrict__ W2,
                  float* __restrict__ out_pre) {
    __shared__ __align__(16) char lds_a[DEPTH * 8192];   // 24 KB
    __shared__ __align__(16) char lds_b[DEPTH * 8192];   // 24 KB

    const int t    = threadIdx.x;
    const int w    = t >> 6;
    const int l    = t & 63;
    const int bm   = blockIdx.x;
    const int bn   = blockIdx.y;
    const int wm   = w >> 1;          // wave row (0..1) -> 64 output rows
    const int wn   = w & 1;           // wave col (0..1) -> 64 output cols
    const int lm   = l & 31;
    const int c0   = (l >> 5) << 1;   // chunk base for this lane's K-half

    f32x16 acc[2][2];
#pragma unroll
    for (int r = 0; r < 16; ++r) {
        acc[0][0][r] = 0.f; acc[0][1][r] = 0.f;
        acc[1][0][r] = 0.f; acc[1][1][r] = 0.f;
    }

    const int nkt = KT_TOTAL;

    // staging (coalesced): wave w stages row-block rb=(w&1) (rows rb*64+l),
    // chunks {w>>1, (w>>1)+2} of each K-step. Chunk-major source: lane l's
    // 16B sits at +l*16 -> contiguous 1KB per instruction.
    const char* gA0 = Xt + (i64)(w >> 1) * XT_CSTRIDE
                         + ((i64)bm * 128 + (w & 1) * 64 + l) * 16;
    const char* gB0 = W1t + (i64)(w >> 1) * W1T_CSTRIDE
                          + ((i64)bn * 128 + (w & 1) * 64 + l) * 16;
    char* lA = lds_a + w * 1024;      // wave-uniform LDS dest base
    char* lB = lds_b + w * 1024;

    // 4 vmcnt events (global_load_lds) per STAGE per thread
#define STAGE(buf, kidx) do {                                             \
        const char* _ga = gA0 + (i64)(kidx) * (4 * XT_CSTRIDE);           \
        const char* _gb = gB0 + (i64)(kidx) * (4 * W1T_CSTRIDE);          \
        char* _la = lA + (buf) * 8192;                                    \
        char* _lb = lB + (buf) * 8192;                                    \
        gload_lds16(_ga,                    _la);                         \
        gload_lds16(_ga + 2 * XT_CSTRIDE,   _la + 4096);                  \
        gload_lds16(_gb,                    _lb);                         \
        gload_lds16(_gb + 2 * W1T_CSTRIDE,  _lb + 4096);                  \
    } while (0)

    STAGE(0, 0);
    STAGE(1, 1);
    STAGE(2, 2);

    int cur = 0;
    for (int kt = 0; kt < nkt; ++kt) {
        // ready-wait for buf[cur]: drain my oldest stage, keep the rest flying
        if (kt + 3 <= nkt)      asm volatile("s_waitcnt vmcnt(8)" ::: "memory");
        else if (kt + 2 == nkt) asm volatile("s_waitcnt vmcnt(4)" ::: "memory");
        else                    asm volatile("s_waitcnt vmcnt(0)" ::: "memory");
        __builtin_amdgcn_s_barrier();          // all waves' quarters landed
        __builtin_amdgcn_sched_barrier(0);

        const char* pa = lds_a + cur * 8192 + c0 * 2048 + (wm * 64 + lm) * 16;
        const char* pb = lds_b + cur * 8192 + c0 * 2048 + (wn * 64 + lm) * 16;
        i32x8 A0, A1, B0, B1;
        *((i32x4*)&A0)     = *(const i32x4*)(pa);
        *((i32x4*)&A0 + 1) = *(const i32x4*)(pa + 2048);
        *((i32x4*)&A1)     = *(const i32x4*)(pa + 512);
        *((i32x4*)&A1 + 1) = *(const i32x4*)(pa + 512 + 2048);
        *((i32x4*)&B0)     = *(const i32x4*)(pb);
        *((i32x4*)&B0 + 1) = *(const i32x4*)(pb + 2048);
        *((i32x4*)&B1)     = *(const i32x4*)(pb + 512);
        *((i32x4*)&B1 + 1) = *(const i32x4*)(pb + 512 + 2048);

        __builtin_amdgcn_s_setprio(1);
        // fmt 0 = OCP fp8 e4m3; unit scales (0x7F = 2^0) in every byte
        acc[0][0] = __builtin_amdgcn_mfma_scale_f32_32x32x64_f8f6f4(
            A0, B0, acc[0][0], 0, 0, 0, 0x7F7F7F7F, 0, 0x7F7F7F7F);
        acc[0][1] = __builtin_amdgcn_mfma_scale_f32_32x32x64_f8f6f4(
            A0, B1, acc[0][1], 0, 0, 0, 0x7F7F7F7F, 0, 0x7F7F7F7F);
        acc[1][0] = __builtin_amdgcn_mfma_scale_f32_32x32x64_f8f6f4(
            A1, B0, acc[1][0], 0, 0, 0, 0x7F7F7F7F, 0, 0x7F7F7F7F);
        acc[1][1] = __builtin_amdgcn_mfma_scale_f32_32x32x64_f8f6f4(
            A1, B1, acc[1][1], 0, 0, 0, 0x7F7F7F7F, 0, 0x7F7F7F7F);
        __builtin_amdgcn_s_setprio(0);

        // my ds_reads retired before anyone overwrites buf[cur]
        asm volatile("s_waitcnt lgkmcnt(0)" ::: "memory");
        __builtin_amdgcn_sched_barrier(0);
        __builtin_amdgcn_s_barrier();          // all waves done reading cur
        __builtin_amdgcn_sched_barrier(0);

        if (kt + 3 < nkt) STAGE(cur, kt + 3);  // refill oldest slot
        cur = (cur == DEPTH - 1) ? 0 : cur + 1;
    }
#undef STAGE

    // ---- fused epilogue ----
    // C/D mapping: col = lane&31, row = (reg&3) + 8*(reg>>2) + 4*(lane>>5).
    const int colbase = bn * 128 + wn * 64 + lm;
    float b1v[2], w2v[2];
#pragma unroll
    for (int cb = 0; cb < 2; ++cb) {
        const int col = colbase + cb * 32;
        const bool ok = col < HID;          // padded cols contribute 0
        b1v[cb] = ok ? b1[col] : 0.f;
        w2v[cb] = ok ? W2[col] : 0.f;
    }
    const int rbase = bm * 128 + wm * 64 + ((l >> 5) << 2);
#pragma unroll
    for (int rb = 0; rb < 2; ++rb)
#pragma unroll
        for (int reg = 0; reg < 16; ++reg) {
            float v = 0.f;
#pragma unroll
            for (int cb = 0; cb < 2; ++cb) {
                const float pre = acc[rb][cb][reg] * W1INV + b1v[cb];
                v += fmaxf(pre, 0.f) * w2v[cb];
            }
            // reduce over this half-wave's 32 columns (masks stay in-half)
            v += __shfl_xor(v, 1);
            v += __shfl_xor(v, 2);
            v += __shfl_xor(v, 4);
            v += __shfl_xor(v, 8);
            v += __shfl_xor(v, 16);
            if (lm == 0) {
                const int row = rbase + rb * 32 + (reg & 3) + ((reg >> 2) << 3);
                atomicAdd(out_pre + row, v);   // device-scope (m20)
            }
        }
}

// ---------------------------------------------------------------------------
// Kernel 3: out[b] = sigmoid(out_pre[b] + b2)
// ---------------------------------------------------------------------------
__global__ void __launch_bounds__(256)
sigmoid_kernel(const float* __restrict__ pre,
               const float* __restrict__ b2,
               float* __restrict__ out) {
    const int i = blockIdx.x * 256 + threadIdx.x;
    out[i] = 1.0f / (1.0f + expf(-(pre[i] + b2[0])));
}

extern "C" void kernel_launch(void* const* d_in, const int* in_sizes, int n_in,
                              void* d_out, int out_size, void* d_ws, size_t ws_size,
                              hipStream_t stream) {
    const float* sim = (const float*)d_in[0];
    const float* W1  = (const float*)d_in[1];
    const float* b1  = (const float*)d_in[2];
    const float* W2  = (const float*)d_in[3];
    const float* b2  = (const float*)d_in[4];
    float* out = (float*)d_out;

    char* ws = (char*)d_ws;
    const i64 X_OFF   = 0;                           // 33,816,576 B
    const i64 W1P_OFF = (i64)BATCH * FEAT;           // fp8: elems == bytes
    const i64 PRE_OFF = W1P_OFF + (i64)HIDP * FEAT;  // +13,737,984
    // total: ~47.6 MB << ws bound
    char*  Xt   = ws + X_OFF;
    char*  W1t  = ws + W1P_OFF;
    float* pre  = (float*)(ws + PRE_OFF);

    prep_kernel<<<BATCH + 5 * HIDP + 1, 256, 0, stream>>>(sim, W1, Xt, W1t, pre);
    {
        dim3 grid(BATCH / 128, HIDP / 128);          // (32, 13)
        gemm_fused_kernel<<<grid, 256, 0, stream>>>(Xt, W1t, b1, W2, pre);
    }
    sigmoid_kernel<<<BATCH / 256, 256, 0, stream>>>(pre, b2, out);
}

// Round 6
// 477.980 us; speedup vs baseline: 1.1115x; 1.0102x over previous
//
#include <hip/hip_runtime.h>
#include <hip/hip_bf16.h>
#include <math.h>

#define MDIM  128
#define FEAT  8256      // 128*129/2 (elements == bytes in fp8)
#define HID   1651
#define HIDP  1664      // 13*128, zero-padded
#define BATCH 4096
#define BK    64
#define KT_TOTAL 129    // FEAT / BK (full K, no split: relu needs full sum)
#define W1SCALE 8192.0f
#define W1INV   (1.0f / 8192.0f)

// W1t chunk-major stride (bytes); B staging stays gload_lds (verified r5)
#define W1T_CSTRIDE ((i64)HIDP * 16)    // 26624
// XA fragment-major: frag(kt,mg) = 2KB at (kt*128+mg)*2048; within: h*1024+lane*16
#define XA_KSTEP ((i64)128 * 2048)      // 262144 B per K-step

using f32x4  = __attribute__((ext_vector_type(4))) float;
using f32x16 = __attribute__((ext_vector_type(16))) float;
using i32x4  = __attribute__((ext_vector_type(4))) int;
using i32x8  = __attribute__((ext_vector_type(8))) int;
typedef long long i64;

__device__ __forceinline__ void gload_lds16(const void* g, void* l) {
    __builtin_amdgcn_global_load_lds(
        (const __attribute__((address_space(1))) void*)g,
        (__attribute__((address_space(3))) void*)l,
        16, 0, 0);
}

__device__ __forceinline__ int row_off(int i) { return (i * (257 - i)) >> 1; }

// pack 8 floats -> 8 fp8 e4m3 bytes (two ints)
__device__ __forceinline__ void pack8_fp8(const float* f, int* o) {
    int lo = __builtin_amdgcn_cvt_pk_fp8_f32(f[0], f[1], 0, false);
    lo     = __builtin_amdgcn_cvt_pk_fp8_f32(f[2], f[3], lo, true);
    int hi = __builtin_amdgcn_cvt_pk_fp8_f32(f[4], f[5], 0, false);
    hi     = __builtin_amdgcn_cvt_pk_fp8_f32(f[6], f[7], hi, true);
    o[0] = lo; o[1] = hi;
}

// ---------------------------------------------------------------------------
// Kernel 1 (fused prep): blocks [0, BATCH) gather triu(sim) -> XA fp8 in
// FRAGMENT-MAJOR layout: the exact per-lane MFMA A-operand bytes, densely
// packed so the GEMM loads A fragments global->VGPR with coalesced dwordx4
// (1KB/instr) and A never touches LDS (round-5 counters: GEMM was LDS-BW
// bound at 48KB/block/K-step; this cuts it to 24KB).
//   row b, K-byte f0: kt=f0>>6, k64=f0&63, lane=(b&31)|((k64>>5)<<5),
//   h=(k64>>4)&1, mg=b>>5, off=(kt*128+mg)*2048 + h*1024 + lane*16 + (k64&15)
// Blocks [BATCH, BATCH+5*HIDP): W1*8192 -> fp8 chunk-major W1t (unchanged).
// Final block zeroes out_pre.
// ---------------------------------------------------------------------------
__global__ void __launch_bounds__(256)
prep_kernel(const float* __restrict__ sim, const float* __restrict__ W1,
            char* __restrict__ XA, char* __restrict__ W1t,
            float* __restrict__ out_pre) {
    const int t = threadIdx.x;
    if (blockIdx.x < BATCH) {
        const int b = blockIdx.x;
        const float* srow = sim + ((i64)b << 14);
        const int mg   = b >> 5;
        const int brow = b & 31;
#pragma unroll
        for (int it = 0; it < 5; ++it) {
            const int g = it * 256 + t;          // 8-elem group id
            if (g < FEAT / 8) {
                const int f0 = g * 8;
                int i = (int)((257.0f - sqrtf(66049.0f - 8.0f * (float)f0)) * 0.5f);
                i = i < 0 ? 0 : (i > 127 ? 127 : i);
                while (i < 127 && row_off(i + 1) <= f0) ++i;
                while (i > 0 && row_off(i) > f0) --i;
                int j = i + (f0 - row_off(i));
                float v[8];
#pragma unroll
                for (int e = 0; e < 8; ++e) {
                    if (j > 127) { ++i; j = i; }
                    v[e] = srow[i * MDIM + j];
                    ++j;
                }
                int o[2];
                pack8_fp8(v, o);
                const int kt   = f0 >> 6;
                const int k64  = f0 & 63;
                const int lane = brow | ((k64 >> 5) << 5);
                const int h    = (k64 >> 4) & 1;
                const i64 off  = ((i64)(kt * 128 + mg) * 2 + h) * 1024
                               + lane * 16 + (k64 & 15);
                *(int2*)(XA + off) = make_int2(o[0], o[1]);
            }
        }
    } else if (blockIdx.x < BATCH + 5 * HIDP) {
        const int c  = blockIdx.x - BATCH;   // 0 .. 5*HIDP-1
        const int wb = c % 5;
        const int n  = c / 5;
        const int g  = wb * 256 + t;
        if (g >= FEAT / 8) return;
        const int f0 = g * 8;
        int o[2];
        if (n < HID) {
            const float* src = W1 + (i64)n * FEAT + f0;
            const f32x4 a = *(const f32x4*)src;
            const f32x4 d = *(const f32x4*)(src + 4);
            float v[8];
#pragma unroll
            for (int e = 0; e < 4; ++e) {
                v[e]     = a[e] * W1SCALE;
                v[e + 4] = d[e] * W1SCALE;
            }
            pack8_fp8(v, o);
        } else {
            o[0] = 0; o[1] = 0;
        }
        *(int2*)(W1t + (i64)(g >> 1) * W1T_CSTRIDE + (i64)n * 16
                    + (g & 1) * 8) = make_int2(o[0], o[1]);
    } else {
        // zero out_pre (4096 floats = 1024 f32x4; 4 per thread)
        const f32x4 zz = {0.f, 0.f, 0.f, 0.f};
        f32x4* p = (f32x4*)out_pre + t * 4;
        p[0] = zz; p[1] = zz; p[2] = zz; p[3] = zz;
    }
}

// ---------------------------------------------------------------------------
// Kernel 2: full-K MX-scaled fp8 GEMM, 128x128 tile, BK=64, fused epilogue.
// Round-6: A fragments load DIRECTLY global->VGPR from fragment-major XA
// (triple-buffered registers, 2-iteration lead, static indices via 3x
// unroll); only B goes through the LDS ring (3 slots, counted vmcnt,
// raw barriers -- verified r2-r5). LDS traffic per block per K-step drops
// 48KB -> 24KB (was the r5 bound). A's K-byte register ordering is
// bit-identical to the old LDS-read path, so numerics are unchanged.
// vmcnt ledger (events/thread/iter: 4 A-loads mid-iter, 2 B-gloads end):
//   steady top-of-iter wait vmcnt(6) = {A(kt+1)x4, B(kt+2)x2} in flight;
//   tail: kt=127 -> 4, kt=128 -> 0. Prologue order B0,B1,A0,A1,B2 makes
//   vmcnt(6) correct from kt=0.
// ---------------------------------------------------------------------------
__global__ void __launch_bounds__(256, 3)
gemm_fused_kernel(const char* __restrict__ XA,
                  const char* __restrict__ W1t,
                  const float* __restrict__ b1,
                  const float* __restrict__ W2,
                  float* __restrict__ out_pre) {
    __shared__ __align__(16) char lds_b[3 * 8192];   // 24 KB (B ring only)

    const int t    = threadIdx.x;
    const int w    = t >> 6;
    const int l    = t & 63;
    const int bm   = blockIdx.x;
    const int bn   = blockIdx.y;
    const int wm   = w >> 1;          // wave row (0..1) -> 64 output rows
    const int wn   = w & 1;           // wave col (0..1) -> 64 output cols
    const int lm   = l & 31;
    const int c0   = (l >> 5) << 1;   // chunk base for this lane's K-half

    f32x16 acc[2][2];
#pragma unroll
    for (int r = 0; r < 16; ++r) {
        acc[0][0][r] = 0.f; acc[0][1][r] = 0.f;
        acc[1][0][r] = 0.f; acc[1][1][r] = 0.f;
    }

    // A-fragment base: frag pair (mg0, mg0+1), mg0 = bm*4 + wm*2.
    // pa(kt) = XA + kt*XA_KSTEP + mg0*2048 + l*16;
    // A0 = {pa+0, pa+1024}, A1 = {pa+2048, pa+3072} (h-major, 1KB coalesced).
    const char* pA0 = XA + (i64)(bm * 4 + wm * 2) * 2048 + l * 16;

    // B staging (verified r5): wave w stages rows (w&1)*64+l, chunks
    // {w>>1, (w>>1)+2}; chunk-major source -> contiguous 1KB per gload.
    const char* gB0 = W1t + (i64)(w >> 1) * W1T_CSTRIDE
                          + ((i64)bn * 128 + (w & 1) * 64 + l) * 16;
    char* lB = lds_b + w * 1024;      // wave-uniform LDS dest base

#define STAGE_B(slot, kidx) do {                                          \
        const char* _gb = gB0 + (i64)(kidx) * (4 * W1T_CSTRIDE);          \
        char* _lb = lB + (slot) * 8192;                                   \
        gload_lds16(_gb,                   _lb);                          \
        gload_lds16(_gb + 2 * W1T_CSTRIDE, _lb + 4096);                   \
    } while (0)

#define LOAD_A(kt, an0, an1) do {                                         \
        const char* _pa = pA0 + (i64)(kt) * XA_KSTEP;                     \
        *((i32x4*)&(an0))     = *(const i32x4*)(_pa);                     \
        *((i32x4*)&(an0) + 1) = *(const i32x4*)(_pa + 1024);              \
        *((i32x4*)&(an1))     = *(const i32x4*)(_pa + 2048);              \
        *((i32x4*)&(an1) + 1) = *(const i32x4*)(_pa + 3072);              \
    } while (0)

#define MFMA4(a0, a1, B0, B1) do {                                        \
        __builtin_amdgcn_s_setprio(1);                                    \
        acc[0][0] = __builtin_amdgcn_mfma_scale_f32_32x32x64_f8f6f4(      \
            (a0), (B0), acc[0][0], 0, 0, 0, 0x7F7F7F7F, 0, 0x7F7F7F7F);   \
        acc[0][1] = __builtin_amdgcn_mfma_scale_f32_32x32x64_f8f6f4(      \
            (a0), (B1), acc[0][1], 0, 0, 0, 0x7F7F7F7F, 0, 0x7F7F7F7F);   \
        acc[1][0] = __builtin_amdgcn_mfma_scale_f32_32x32x64_f8f6f4(      \
            (a1), (B0), acc[1][0], 0, 0, 0, 0x7F7F7F7F, 0, 0x7F7F7F7F);   \
        acc[1][1] = __builtin_amdgcn_mfma_scale_f32_32x32x64_f8f6f4(      \
            (a1), (B1), acc[1][1], 0, 0, 0, 0x7F7F7F7F, 0, 0x7F7F7F7F);   \
        __builtin_amdgcn_s_setprio(0);                                    \
    } while (0)

    // ITER: WAIT is a string literal vmcnt count; slot is a literal 0/1/2.
#define ITER(kt, slot, ac0, ac1, an0, an1, DOLOAD, DOSTAGE, WAIT) do {    \
        asm volatile("s_waitcnt vmcnt(" WAIT ")" ::: "memory");           \
        __builtin_amdgcn_s_barrier();          /* B(kt) visible to all */ \
        __builtin_amdgcn_sched_barrier(0);                                \
        const char* _pb = lds_b + (slot) * 8192 + c0 * 2048               \
                        + (wn * 64 + lm) * 16;                            \
        i32x8 B0, B1;                                                     \
        *((i32x4*)&B0)     = *(const i32x4*)(_pb);                        \
        *((i32x4*)&B0 + 1) = *(const i32x4*)(_pb + 2048);                 \
        *((i32x4*)&B1)     = *(const i32x4*)(_pb + 512);                  \
        *((i32x4*)&B1 + 1) = *(const i32x4*)(_pb + 512 + 2048);           \
        if (DOLOAD) LOAD_A((kt) + 2, an0, an1);                           \
        MFMA4(ac0, ac1, B0, B1);                                          \
        asm volatile("s_waitcnt lgkmcnt(0)" ::: "memory");                \
        __builtin_amdgcn_sched_barrier(0);                                \
        __builtin_amdgcn_s_barrier();          /* slot free to refill */  \
        __builtin_amdgcn_sched_barrier(0);                                \
        if (DOSTAGE) STAGE_B(slot, (kt) + 3);                             \
    } while (0)

    i32x8 a0A, a1A, a0B, a1B, a0C, a1C;   // A reg ring, static-indexed

    // prologue (event order B0,B1,A0,A1,B2 -> vmcnt(6) valid from kt=0)
    STAGE_B(0, 0);
    STAGE_B(1, 1);
    LOAD_A(0, a0A, a1A);
    LOAD_A(1, a0B, a1B);
    STAGE_B(2, 2);

    // main loop: kt = 0..125 (42 unrolled triples), fully steady-state
    for (int kt3 = 0; kt3 < 126; kt3 += 3) {
        ITER(kt3 + 0, 0, a0A, a1A, a0C, a1C, 1, 1, "6");
        ITER(kt3 + 1, 1, a0B, a1B, a0A, a1A, 1, 1, "6");
        ITER(kt3 + 2, 2, a0C, a1C, a0B, a1B, 1, 1, "6");
    }
    // tail: kt = 126, 127, 128
    ITER(126, 0, a0A, a1A, a0C, a1C, 1, 0, "6");   // loads A(128)
    ITER(127, 1, a0B, a1B, a0A, a1A, 0, 0, "4");
    ITER(128, 2, a0C, a1C, a0A, a1A, 0, 0, "0");

#undef ITER
#undef MFMA4
#undef LOAD_A
#undef STAGE_B

    // ---- fused epilogue ----
    // C/D mapping: col = lane&31, row = (reg&3) + 8*(reg>>2) + 4*(lane>>5).
    const int colbase = bn * 128 + wn * 64 + lm;
    float b1v[2], w2v[2];
#pragma unroll
    for (int cb = 0; cb < 2; ++cb) {
        const int col = colbase + cb * 32;
        const bool ok = col < HID;          // padded cols contribute 0
        b1v[cb] = ok ? b1[col] : 0.f;
        w2v[cb] = ok ? W2[col] : 0.f;
    }
    const int rbase = bm * 128 + wm * 64 + ((l >> 5) << 2);
#pragma unroll
    for (int rb = 0; rb < 2; ++rb)
#pragma unroll
        for (int reg = 0; reg < 16; ++reg) {
            float v = 0.f;
#pragma unroll
            for (int cb = 0; cb < 2; ++cb) {
                const float pre = acc[rb][cb][reg] * W1INV + b1v[cb];
                v += fmaxf(pre, 0.f) * w2v[cb];
            }
            // reduce over this half-wave's 32 columns (masks stay in-half)
            v += __shfl_xor(v, 1);
            v += __shfl_xor(v, 2);
            v += __shfl_xor(v, 4);
            v += __shfl_xor(v, 8);
            v += __shfl_xor(v, 16);
            if (lm == 0) {
                const int row = rbase + rb * 32 + (reg & 3) + ((reg >> 2) << 3);
                atomicAdd(out_pre + row, v);   // device-scope (m20)
            }
        }
}

// ---------------------------------------------------------------------------
// Kernel 3: out[b] = sigmoid(out_pre[b] + b2)
// ---------------------------------------------------------------------------
__global__ void __launch_bounds__(256)
sigmoid_kernel(const float* __restrict__ pre,
               const float* __restrict__ b2,
               float* __restrict__ out) {
    const int i = blockIdx.x * 256 + threadIdx.x;
    out[i] = 1.0f / (1.0f + expf(-(pre[i] + b2[0])));
}

extern "C" void kernel_launch(void* const* d_in, const int* in_sizes, int n_in,
                              void* d_out, int out_size, void* d_ws, size_t ws_size,
                              hipStream_t stream) {
    const float* sim = (const float*)d_in[0];
    const float* W1  = (const float*)d_in[1];
    const float* b1  = (const float*)d_in[2];
    const float* W2  = (const float*)d_in[3];
    const float* b2  = (const float*)d_in[4];
    float* out = (float*)d_out;

    char* ws = (char*)d_ws;
    const i64 X_OFF   = 0;                           // 33,816,576 B
    const i64 W1P_OFF = (i64)BATCH * FEAT;           // fp8: elems == bytes
    const i64 PRE_OFF = W1P_OFF + (i64)HIDP * FEAT;  // +13,737,984
    // total: ~47.6 MB << ws bound
    char*  XA   = ws + X_OFF;
    char*  W1t  = ws + W1P_OFF;
    float* pre  = (float*)(ws + PRE_OFF);

    prep_kernel<<<BATCH + 5 * HIDP + 1, 256, 0, stream>>>(sim, W1, XA, W1t, pre);
    {
        dim3 grid(BATCH / 128, HIDP / 128);          // (32, 13)
        gemm_fused_kernel<<<grid, 256, 0, stream>>>(XA, W1t, b1, W2, pre);
    }
    sigmoid_kernel<<<BATCH / 256, 256, 0, stream>>>(pre, b2, out);
}